// Round 4
// baseline (188.361 us; speedup 1.0000x reference)
//
#include <hip/hip_runtime.h>
#include <hip/hip_bf16.h>

#define ALPHA 0.2f
#define L2E 1.4426950408889634f

constexpr int Nn = 4096;
constexpr int FIN = 256;
constexpr int FOUT = 128;

typedef __attribute__((ext_vector_type(8))) short short8;
typedef __attribute__((ext_vector_type(8))) unsigned short ushort8;
typedef __attribute__((ext_vector_type(4))) float f32x4;
typedef __attribute__((ext_vector_type(16))) float f32x16;
typedef __attribute__((ext_vector_type(4))) int int4v;

__device__ __forceinline__ unsigned short f2bf(float x) {
  unsigned int u = __float_as_uint(x);
  unsigned int r = (u + 0x7fffu + ((u >> 16) & 1u)) >> 16;
  return (unsigned short)r;
}

__device__ __forceinline__ void gload16(const void* g, void* l) {
  auto lp = (__attribute__((address_space(3))) void*)l;
  auto gp = (const __attribute__((address_space(1))) void*)g;
  __builtin_amdgcn_global_load_lds(gp, lp, 16, 0, 0);
}

// ---------------------------------------------------------------------------
// k0: blocks 0..7: WT bf16 [i=128][k=256] from W f32 [k][i] (LDS transpose).
//     block 8: wa1[k] = sum_i W[k][i]*a[i], wa2[k] = sum_i W[k][i]*a[128+i].
// ---------------------------------------------------------------------------
__global__ __launch_bounds__(256) void k0_prep(
    const float* __restrict__ W, const float* __restrict__ a,
    unsigned short* __restrict__ WT, float* __restrict__ wa) {
  int t = threadIdx.x;
  int blk = blockIdx.x;
  if (blk < 8) {
    __shared__ float lw[32][132];
    int kc0 = blk * 32;
#pragma unroll
    for (int m = 0; m < 4; ++m) {
      int idx = t * 16 + m * 4;
      f32x4 v = *(const f32x4*)(W + kc0 * 128 + idx);
      int k = idx >> 7, i0 = idx & 127;
      *(f32x4*)&lw[k][i0] = v;
    }
    __syncthreads();
    int i = t >> 1, half = t & 1;
    unsigned short pk[16];
#pragma unroll
    for (int kk = 0; kk < 16; ++kk) pk[kk] = f2bf(lw[half * 16 + kk][i]);
    ushort8* dst = (ushort8*)(WT + i * 256 + kc0 + half * 16);
    dst[0] = *(ushort8*)&pk[0];
    dst[1] = *(ushort8*)&pk[8];
  } else {
    float acc1 = 0.f, acc2 = 0.f;
    const float* Wr = W + t * 128;
#pragma unroll
    for (int m = 0; m < 32; ++m) {
      f32x4 wv = *(const f32x4*)(Wr + m * 4);
      f32x4 a1 = *(const f32x4*)(a + m * 4);
      f32x4 a2 = *(const f32x4*)(a + 128 + m * 4);
      acc1 += wv.x * a1.x + wv.y * a1.y + wv.z * a1.z + wv.w * a1.w;
      acc2 += wv.x * a2.x + wv.y * a2.y + wv.z * a2.z + wv.w * a2.w;
    }
    wa[t] = acc1;
    wa[256 + t] = acc2;
  }
}

// ---------------------------------------------------------------------------
// k1a: exact f32, prescaled by log2(e): s1L = (h·wa1)*L2E, s2L = (h·wa2)*L2E.
// ---------------------------------------------------------------------------
__global__ __launch_bounds__(256) void k1a_scores(
    const float* __restrict__ h, const float* __restrict__ wa,
    float* __restrict__ s1L, float* __restrict__ s2L) {
  int t = threadIdx.x;
  int wv = t >> 6, l = t & 63;
  int row = blockIdx.x * 4 + wv;
  f32x4 hv = *(const f32x4*)(h + (long long)row * 256 + l * 4);
  f32x4 w1 = ((const f32x4*)wa)[l];
  f32x4 w2 = ((const f32x4*)wa)[64 + l];
  float v1 = hv.x * w1.x + hv.y * w1.y + hv.z * w1.z + hv.w * w1.w;
  float v2 = hv.x * w2.x + hv.y * w2.y + hv.z * w2.z + hv.w * w2.w;
#pragma unroll
  for (int off = 32; off; off >>= 1) {
    v1 += __shfl_xor(v1, off);
    v2 += __shfl_xor(v2, off);
  }
  if (l == 0) {
    s1L[row] = v1 * L2E;
    s2L[row] = v2 * L2E;
  }
}

// ---------------------------------------------------------------------------
// k1b: Wh via mfma_16x16x32_bf16; emits whT bf16 [b][i=128][n=4096].
// ---------------------------------------------------------------------------
__global__ __launch_bounds__(256) void k1b_wh(
    const float* __restrict__ h, const unsigned short* __restrict__ WT,
    unsigned short* __restrict__ whT) {
  __shared__ __align__(16) char smem[49152];
  int t = threadIdx.x;
  int w = t >> 6, l = t & 63, g = l >> 4, r = l & 15;
  int r0 = blockIdx.x * 64;
  int b = r0 >> 12, nbase = r0 & 4095;

  f32x4 acc[8];
#pragma unroll
  for (int s = 0; s < 8; ++s) acc[s] = (f32x4){0.f, 0.f, 0.f, 0.f};

  for (int kc = 0; kc < 2; ++kc) {
    __syncthreads();
    {
      int row = t >> 2, q4 = t & 3;
      const f32x4* src =
          (const f32x4*)(h + (long long)(r0 + row) * 256 + kc * 128 + q4 * 32);
#pragma unroll
      for (int m = 0; m < 4; ++m) {
        f32x4 v0 = src[m * 2], v1 = src[m * 2 + 1];
        unsigned int pk[4];
        pk[0] = ((unsigned)f2bf(v0.y) << 16) | f2bf(v0.x);
        pk[1] = ((unsigned)f2bf(v0.w) << 16) | f2bf(v0.z);
        pk[2] = ((unsigned)f2bf(v1.y) << 16) | f2bf(v1.x);
        pk[3] = ((unsigned)f2bf(v1.w) << 16) | f2bf(v1.z);
        int slot = q4 * 4 + m;
        *(ushort8*)(smem + row * 256 + ((slot ^ (row & 7)) << 4)) =
            *(ushort8*)pk;
      }
    }
    {
      int i = t >> 1, pt = t & 1;
      const ushort8* src = (const ushort8*)(WT + i * 256 + kc * 128 + pt * 64);
#pragma unroll
      for (int m = 0; m < 8; ++m) {
        ushort8 v = src[m];
        int slot = pt * 8 + m;
        *(ushort8*)(smem + 16384 + i * 256 + ((slot ^ (i & 7)) << 4)) = v;
      }
    }
    __syncthreads();
#pragma unroll
    for (int kk = 0; kk < 4; ++kk) {
      int arow = w * 16 + r;
      short8 af = *(const short8*)(smem + arow * 256 +
                                   (((kk * 4 + g) ^ (arow & 7)) << 4));
#pragma unroll
      for (int s = 0; s < 8; ++s) {
        int i = s * 16 + r;
        short8 bf = *(const short8*)(smem + 16384 + i * 256 +
                                     (((kk * 4 + g) ^ (i & 7)) << 4));
        acc[s] =
            __builtin_amdgcn_mfma_f32_16x16x32_bf16(af, bf, acc[s], 0, 0, 0);
      }
    }
  }

  __syncthreads();
  unsigned short* tb = (unsigned short*)smem;  // [128][72]
#pragma unroll
  for (int s = 0; s < 8; ++s)
#pragma unroll
    for (int q = 0; q < 4; ++q)
      tb[(s * 16 + r) * 72 + w * 16 + 4 * g + q] = f2bf(acc[s][q]);
  __syncthreads();
  {
    int i = t >> 1, half = t & 1;
    const ushort8* src = (const ushort8*)(tb + i * 72 + half * 32);
    ushort8* dst = (ushort8*)(whT + (((long long)(b * 128 + i)) << 12) + nbase +
                              half * 32);
#pragma unroll
    for (int m = 0; m < 4; ++m) dst[m] = src[m];
  }
}

// ---------------------------------------------------------------------------
// k2: wave-per-row, single-pass: bits (1 ull/lane), S = sum masked exp2(vL).
// st2[row] = {s1L, -log2(S)}. Grid 4096 x 256 (4 rows/block). No LDS/barriers.
// ---------------------------------------------------------------------------
__global__ __launch_bounds__(256) void k2_stats(
    const int* __restrict__ adj, const float* __restrict__ s1L,
    const float* __restrict__ s2L, float2* __restrict__ st2,
    unsigned long long* __restrict__ mask64) {
  int t = threadIdx.x;
  int w = t >> 6, l = t & 63;
  int row = blockIdx.x * 4 + w;
  int b = row >> 12;
  float s1j = s1L[row];
  const int4v* arow = (const int4v*)(adj + (long long)row * Nn) + l * 16;
  const f32x4* s2v = (const f32x4*)(s2L + (b << 12)) + l * 16;

  unsigned long long bits = 0;
  float sum = 0.f;
#pragma unroll
  for (int q = 0; q < 16; ++q) {
    int4v av = arow[q];
    f32x4 sv = s2v[q];
#pragma unroll
    for (int c = 0; c < 4; ++c) {
      float u = s1j + sv[c];
      float vL = fmaxf(u, ALPHA * u);
      float e = exp2f(vL);
      bits |= ((unsigned long long)(unsigned)av[c]) << (q * 4 + c);
      sum += av[c] ? e : 0.f;
    }
  }
  mask64[((long long)row << 6) + l] = bits;
#pragma unroll
  for (int off = 32; off; off >>= 1) sum += __shfl_xor(sum, off);
  if (l == 0) {
    float negc = (sum > 0.f) ? -log2f(sum) : -1.0e30f;
    st2[row] = make_float2(s1j, negc);
  }
}

// ---------------------------------------------------------------------------
// k3: out[b,k,i] = elu( sum_j p[j,k]*Wh[j,i] ), fully fused.
// Grid 256 (b x 64 k-tiles of 64), 1024 threads = 16 waves = 2 ks x 8 jq.
// LDS 128KB: wt dbuf 2x32K @0, mask ull[4096] @64K, st2 float2[4096] @96K.
// whT staged via global_load_lds (pre-swizzled source, linear dest).
// ---------------------------------------------------------------------------
__global__ __launch_bounds__(1024) void k3_pv(
    const unsigned short* __restrict__ whT, const float2* __restrict__ st2,
    const unsigned long long* __restrict__ mask64,
    const float* __restrict__ s2L, float* __restrict__ out) {
  __shared__ __align__(16) char smem[131072];
  unsigned int* mkw = (unsigned int*)(smem + 65536);
  float2* stl = (float2*)(smem + 98304);

  int t = threadIdx.x;
  int blk = blockIdx.x;
  int b = blk >> 6, kt = blk & 63;
  int k0 = kt << 6;
  int w = t >> 6, l = t & 63, hl = l >> 5, ln = l & 31;
  int ks = w & 1, jq = w >> 1;
  int kg = k0 + ks * 32 + ln;
  float s2k = s2L[(b << 12) + kg];

  // startup: stage mask word + st2 for all 4096 j
  {
    unsigned long long* mk64 = (unsigned long long*)(smem + 65536);
#pragma unroll
    for (int m = 0; m < 4; ++m) {
      int j = m * 1024 + t;
      mk64[j] = mask64[(((long long)(b << 12) + j) << 6) + kt];
      stl[j] = st2[(b << 12) + j];
    }
  }

  // whT chunk staging: wave w -> rows [w*8, w*8+8), 2 calls x (4 rows = 1KB).
  // lane l: row = w*8 + h*4 + (l>>4), psl = l&15, src slot s = psl ^ ((3*row)&7)
  const unsigned short* whTb = whT + (((long long)b * 128) << 12);
  int row0 = w * 8 + (l >> 4);
  int psl = l & 15;
#pragma unroll
  for (int hh = 0; hh < 2; ++hh) {
    int rr = row0 + hh * 4;
    int s = psl ^ ((3 * rr) & 7);
    gload16(whTb + ((long long)rr << 12) + 0 + s * 8,
            smem + (w * 8 + hh * 4) * 256);
  }
  __syncthreads();

  f32x16 acc[4];
#pragma unroll
  for (int q = 0; q < 4; ++q)
#pragma unroll
    for (int rr = 0; rr < 16; ++rr) acc[q][rr] = 0.f;

  int sbase = jq * 2 + hl;  // this wave's j16-slot within a chunk
  for (int c = 0; c < 32; ++c) {
    int cur = c & 1;
    char* wcur = smem + cur * 32768;
    if (c < 31) {
      int j0 = (c + 1) * 128;
      char* wnxt = smem + (cur ^ 1) * 32768;
#pragma unroll
      for (int hh = 0; hh < 2; ++hh) {
        int rr = row0 + hh * 4;
        int s = psl ^ ((3 * rr) & 7);
        gload16(whTb + ((long long)rr << 12) + j0 + s * 8,
                wnxt + (w * 8 + hh * 4) * 256);
      }
    }

    // A fragment: 8 exps, j_abs = c*128 + sbase*8 + e
    short8 af;
    int jb = c * 128 + sbase * 8;
#pragma unroll
    for (int e = 0; e < 8; ++e) {
      int ja = jb + e;
      float2 sc = stl[ja];
      unsigned int mv = mkw[ja * 2 + ks];
      float u = sc.x + s2k;
      float vL = fmaxf(u, ALPHA * u);
      float p = exp2f(vL + sc.y);
      p = ((mv >> ln) & 1u) ? p : 0.f;
      __hip_bfloat16 hb = __float2bfloat16(p);
      af[e] = *(short*)&hb;
    }
#pragma unroll
    for (int q = 0; q < 4; ++q) {
      int i = q * 32 + ln;
      short8 bv =
          *(const short8*)(wcur + i * 256 + ((sbase ^ ((3 * i) & 7)) << 4));
      acc[q] = __builtin_amdgcn_mfma_f32_32x32x16_bf16(af, bv, acc[q], 0, 0, 0);
    }
    __syncthreads();
  }

  // ---- 3-level tree reduce over jq (zone = whole smem, 8 x 16KB regions) ----
  float* zone = (float*)smem;
  // level 1: jq odd -> jq even
  if (jq & 1) {
    int rid = ks * 4 + (jq >> 1);
#pragma unroll
    for (int q = 0; q < 4; ++q)
#pragma unroll
      for (int r4 = 0; r4 < 4; ++r4) {
        f32x4 v = {acc[q][r4 * 4], acc[q][r4 * 4 + 1], acc[q][r4 * 4 + 2],
                   acc[q][r4 * 4 + 3]};
        *(f32x4*)&zone[rid * 4096 + (q * 4 + r4) * 256 + l * 4] = v;
      }
  }
  __syncthreads();
  if (!(jq & 1)) {
    int rid = ks * 4 + (jq >> 1);
#pragma unroll
    for (int q = 0; q < 4; ++q)
#pragma unroll
      for (int r4 = 0; r4 < 4; ++r4) {
        f32x4 v = *(f32x4*)&zone[rid * 4096 + (q * 4 + r4) * 256 + l * 4];
        acc[q][r4 * 4] += v.x;
        acc[q][r4 * 4 + 1] += v.y;
        acc[q][r4 * 4 + 2] += v.z;
        acc[q][r4 * 4 + 3] += v.w;
      }
  }
  __syncthreads();
  // level 2: jq in {2,6} -> {0,4}
  if (!(jq & 1) && (jq & 2)) {
    int rid = ks * 2 + (jq >> 2);
#pragma unroll
    for (int q = 0; q < 4; ++q)
#pragma unroll
      for (int r4 = 0; r4 < 4; ++r4) {
        f32x4 v = {acc[q][r4 * 4], acc[q][r4 * 4 + 1], acc[q][r4 * 4 + 2],
                   acc[q][r4 * 4 + 3]};
        *(f32x4*)&zone[rid * 4096 + (q * 4 + r4) * 256 + l * 4] = v;
      }
  }
  __syncthreads();
  if (!(jq & 3)) {
    int rid = ks * 2 + (jq >> 2);
#pragma unroll
    for (int q = 0; q < 4; ++q)
#pragma unroll
      for (int r4 = 0; r4 < 4; ++r4) {
        f32x4 v = *(f32x4*)&zone[rid * 4096 + (q * 4 + r4) * 256 + l * 4];
        acc[q][r4 * 4] += v.x;
        acc[q][r4 * 4 + 1] += v.y;
        acc[q][r4 * 4 + 2] += v.z;
        acc[q][r4 * 4 + 3] += v.w;
      }
  }
  __syncthreads();
  // level 3: jq==4 -> jq==0
  if (jq == 4) {
#pragma unroll
    for (int q = 0; q < 4; ++q)
#pragma unroll
      for (int r4 = 0; r4 < 4; ++r4) {
        f32x4 v = {acc[q][r4 * 4], acc[q][r4 * 4 + 1], acc[q][r4 * 4 + 2],
                   acc[q][r4 * 4 + 3]};
        *(f32x4*)&zone[ks * 4096 + (q * 4 + r4) * 256 + l * 4] = v;
      }
  }
  __syncthreads();
  if (jq == 0) {
#pragma unroll
    for (int q = 0; q < 4; ++q)
#pragma unroll
      for (int r4 = 0; r4 < 4; ++r4) {
        f32x4 v = *(f32x4*)&zone[ks * 4096 + (q * 4 + r4) * 256 + l * 4];
        acc[q][r4 * 4] += v.x;
        acc[q][r4 * 4 + 1] += v.y;
        acc[q][r4 * 4 + 2] += v.z;
        acc[q][r4 * 4 + 3] += v.w;
      }
    // epilogue: ELU + store
#pragma unroll
    for (int q = 0; q < 4; ++q) {
      int i = q * 32 + ln;
#pragma unroll
      for (int rr = 0; rr < 16; ++rr) {
        int kl = (rr & 3) + ((rr >> 2) << 3) + (hl << 2);
        int krow = k0 + ks * 32 + kl;
        float x = acc[q][rr];
        float y = x > 0.f ? x : expm1f(x);
        out[(((long long)(b << 12) + krow) << 7) + i] = y;
      }
    }
  }
}

extern "C" void kernel_launch(void* const* d_in, const int* in_sizes, int n_in,
                              void* d_out, int out_size, void* d_ws,
                              size_t ws_size, hipStream_t stream) {
  const float* h = (const float*)d_in[0];
  const int* adj = (const int*)d_in[1];
  const float* W = (const float*)d_in[2];
  const float* a = (const float*)d_in[3];
  float* out = (float*)d_out;

  char* ws = (char*)d_ws;
  unsigned short* WT = (unsigned short*)ws;                  // 64 KB
  float* wa = (float*)(ws + 65536);                          // 2 KB
  unsigned short* whT = (unsigned short*)(ws + (1 << 20));   // 4 MB
  float* s1L = (float*)(ws + (5 << 20));                     // 64 KB
  float* s2L = s1L + 16384;                                  // 64 KB
  float2* st2 = (float2*)(ws + (5 << 20) + (128 << 10));     // 128 KB
  unsigned long long* mask64 =
      (unsigned long long*)(ws + (6 << 20));                 // 8 MB

  hipLaunchKernelGGL(k0_prep, dim3(9), dim3(256), 0, stream, W, a, WT, wa);
  hipLaunchKernelGGL(k1a_scores, dim3(4096), dim3(256), 0, stream, h, wa, s1L,
                     s2L);
  hipLaunchKernelGGL(k1b_wh, dim3(256), dim3(256), 0, stream, h, WT, whT);
  hipLaunchKernelGGL(k2_stats, dim3(4096), dim3(256), 0, stream, adj, s1L, s2L,
                     st2, mask64);
  hipLaunchKernelGGL(k3_pv, dim3(256), dim3(1024), 0, stream, whT, st2, mask64,
                     s2L, out);
}

// Round 5
// 128.787 us; speedup vs baseline: 1.4626x; 1.4626x over previous
//
#include <hip/hip_runtime.h>
#include <hip/hip_bf16.h>

#define ALPHA 0.2f
#define L2E 1.4426950408889634f

constexpr int Nn = 4096;
constexpr int FIN = 256;
constexpr int FOUT = 128;
constexpr int JC = 8;    // j-split for k3
constexpr int JQ = 512;  // j per k3 block
constexpr int NCH = 16;  // 32-j chunks per block
constexpr long long SLAB = 2097152;  // 4*4096*128 elems per partial slab

typedef __attribute__((ext_vector_type(8))) short short8;
typedef __attribute__((ext_vector_type(8))) unsigned short ushort8;
typedef __attribute__((ext_vector_type(4))) float f32x4;
typedef __attribute__((ext_vector_type(16))) float f32x16;
typedef __attribute__((ext_vector_type(4))) int int4v;

__device__ __forceinline__ unsigned short f2bf(float x) {
  unsigned int u = __float_as_uint(x);
  unsigned int r = (u + 0x7fffu + ((u >> 16) & 1u)) >> 16;
  return (unsigned short)r;
}

__device__ __forceinline__ void gload16(const void* g, void* l) {
  auto lp = (__attribute__((address_space(3))) void*)l;
  auto gp = (const __attribute__((address_space(1))) void*)g;
  __builtin_amdgcn_global_load_lds(gp, lp, 16, 0, 0);
}

// ---------------------------------------------------------------------------
// k0: blocks 0..7: WT bf16 [i=128][k=256] from W f32 [k][i] (LDS transpose).
//     block 8: wa1[k] = sum_i W[k][i]*a[i], wa2[k] = sum_i W[k][i]*a[128+i].
// ---------------------------------------------------------------------------
__global__ __launch_bounds__(256) void k0_prep(
    const float* __restrict__ W, const float* __restrict__ a,
    unsigned short* __restrict__ WT, float* __restrict__ wa) {
  int t = threadIdx.x;
  int blk = blockIdx.x;
  if (blk < 8) {
    __shared__ float lw[32][132];
    int kc0 = blk * 32;
#pragma unroll
    for (int m = 0; m < 4; ++m) {
      int idx = t * 16 + m * 4;
      f32x4 v = *(const f32x4*)(W + kc0 * 128 + idx);
      int k = idx >> 7, i0 = idx & 127;
      *(f32x4*)&lw[k][i0] = v;
    }
    __syncthreads();
    int i = t >> 1, half = t & 1;
    unsigned short pk[16];
#pragma unroll
    for (int kk = 0; kk < 16; ++kk) pk[kk] = f2bf(lw[half * 16 + kk][i]);
    ushort8* dst = (ushort8*)(WT + i * 256 + kc0 + half * 16);
    dst[0] = *(ushort8*)&pk[0];
    dst[1] = *(ushort8*)&pk[8];
  } else {
    float acc1 = 0.f, acc2 = 0.f;
    const float* Wr = W + t * 128;
#pragma unroll
    for (int m = 0; m < 32; ++m) {
      f32x4 wv = *(const f32x4*)(Wr + m * 4);
      f32x4 a1 = *(const f32x4*)(a + m * 4);
      f32x4 a2 = *(const f32x4*)(a + 128 + m * 4);
      acc1 += wv.x * a1.x + wv.y * a1.y + wv.z * a1.z + wv.w * a1.w;
      acc2 += wv.x * a2.x + wv.y * a2.y + wv.z * a2.z + wv.w * a2.w;
    }
    wa[t] = acc1;
    wa[256 + t] = acc2;
  }
}

// ---------------------------------------------------------------------------
// k1a: exact f32, prescaled by log2(e): s1L = (h·wa1)*L2E, s2L = (h·wa2)*L2E.
// ---------------------------------------------------------------------------
__global__ __launch_bounds__(256) void k1a_scores(
    const float* __restrict__ h, const float* __restrict__ wa,
    float* __restrict__ s1L, float* __restrict__ s2L) {
  int t = threadIdx.x;
  int wv = t >> 6, l = t & 63;
  int row = blockIdx.x * 4 + wv;
  f32x4 hv = *(const f32x4*)(h + (long long)row * 256 + l * 4);
  f32x4 w1 = ((const f32x4*)wa)[l];
  f32x4 w2 = ((const f32x4*)wa)[64 + l];
  float v1 = hv.x * w1.x + hv.y * w1.y + hv.z * w1.z + hv.w * w1.w;
  float v2 = hv.x * w2.x + hv.y * w2.y + hv.z * w2.z + hv.w * w2.w;
#pragma unroll
  for (int off = 32; off; off >>= 1) {
    v1 += __shfl_xor(v1, off);
    v2 += __shfl_xor(v2, off);
  }
  if (l == 0) {
    s1L[row] = v1 * L2E;
    s2L[row] = v2 * L2E;
  }
}

// ---------------------------------------------------------------------------
// k1b: Wh via mfma_16x16x32_bf16; emits whT bf16 [b][i=128][n=4096].
// ---------------------------------------------------------------------------
__global__ __launch_bounds__(256) void k1b_wh(
    const float* __restrict__ h, const unsigned short* __restrict__ WT,
    unsigned short* __restrict__ whT) {
  __shared__ __align__(16) char smem[49152];
  int t = threadIdx.x;
  int w = t >> 6, l = t & 63, g = l >> 4, r = l & 15;
  int r0 = blockIdx.x * 64;
  int b = r0 >> 12, nbase = r0 & 4095;

  f32x4 acc[8];
#pragma unroll
  for (int s = 0; s < 8; ++s) acc[s] = (f32x4){0.f, 0.f, 0.f, 0.f};

  for (int kc = 0; kc < 2; ++kc) {
    __syncthreads();
    {
      int row = t >> 2, q4 = t & 3;
      const f32x4* src =
          (const f32x4*)(h + (long long)(r0 + row) * 256 + kc * 128 + q4 * 32);
#pragma unroll
      for (int m = 0; m < 4; ++m) {
        f32x4 v0 = src[m * 2], v1 = src[m * 2 + 1];
        unsigned int pk[4];
        pk[0] = ((unsigned)f2bf(v0.y) << 16) | f2bf(v0.x);
        pk[1] = ((unsigned)f2bf(v0.w) << 16) | f2bf(v0.z);
        pk[2] = ((unsigned)f2bf(v1.y) << 16) | f2bf(v1.x);
        pk[3] = ((unsigned)f2bf(v1.w) << 16) | f2bf(v1.z);
        int slot = q4 * 4 + m;
        *(ushort8*)(smem + row * 256 + ((slot ^ (row & 7)) << 4)) =
            *(ushort8*)pk;
      }
    }
    {
      int i = t >> 1, pt = t & 1;
      const ushort8* src = (const ushort8*)(WT + i * 256 + kc * 128 + pt * 64);
#pragma unroll
      for (int m = 0; m < 8; ++m) {
        ushort8 v = src[m];
        int slot = pt * 8 + m;
        *(ushort8*)(smem + 16384 + i * 256 + ((slot ^ (i & 7)) << 4)) = v;
      }
    }
    __syncthreads();
#pragma unroll
    for (int kk = 0; kk < 4; ++kk) {
      int arow = w * 16 + r;
      short8 af = *(const short8*)(smem + arow * 256 +
                                   (((kk * 4 + g) ^ (arow & 7)) << 4));
#pragma unroll
      for (int s = 0; s < 8; ++s) {
        int i = s * 16 + r;
        short8 bf = *(const short8*)(smem + 16384 + i * 256 +
                                     (((kk * 4 + g) ^ (i & 7)) << 4));
        acc[s] =
            __builtin_amdgcn_mfma_f32_16x16x32_bf16(af, bf, acc[s], 0, 0, 0);
      }
    }
  }

  __syncthreads();
  unsigned short* tb = (unsigned short*)smem;  // [128][72]
#pragma unroll
  for (int s = 0; s < 8; ++s)
#pragma unroll
    for (int q = 0; q < 4; ++q)
      tb[(s * 16 + r) * 72 + w * 16 + 4 * g + q] = f2bf(acc[s][q]);
  __syncthreads();
  {
    int i = t >> 1, half = t & 1;
    const ushort8* src = (const ushort8*)(tb + i * 72 + half * 32);
    ushort8* dst = (ushort8*)(whT + (((long long)(b * 128 + i)) << 12) + nbase +
                              half * 32);
#pragma unroll
    for (int m = 0; m < 4; ++m) dst[m] = src[m];
  }
}

// ---------------------------------------------------------------------------
// k2: block-per-row, coalesced int4 adj loads (idx q*256+t), single-pass
// no-max softmax in exp2 domain; mask bits packed via shfl_xor nibble merge.
// st2[row] = {s1L, -log2(S)}; mask64[row][64] ull. Grid 16384 x 256.
// ---------------------------------------------------------------------------
__global__ __launch_bounds__(256) void k2_stats(
    const int* __restrict__ adj, const float* __restrict__ s1L,
    const float* __restrict__ s2L, float2* __restrict__ st2,
    unsigned long long* __restrict__ mask64) {
  __shared__ unsigned int mwords[128];
  __shared__ float wsum[4];
  int row = blockIdx.x;
  int b = row >> 12;
  int t = threadIdx.x;
  float s1j = s1L[row];
  const int4v* arow = (const int4v*)(adj + (long long)row * Nn);
  const f32x4* s2v = (const f32x4*)(s2L + (b << 12));

  float sum = 0.f;
#pragma unroll
  for (int q = 0; q < 4; ++q) {
    int4v av = arow[q * 256 + t];   // k = 1024q + 4t + c  (coalesced)
    f32x4 sv = s2v[q * 256 + t];
    unsigned nib = 0;
#pragma unroll
    for (int c = 0; c < 4; ++c) {
      float u = s1j + sv[c];
      float vL = fmaxf(u, ALPHA * u);
      float e = exp2f(vL);
      sum += (av[c] > 0) ? e : 0.f;
      nib |= ((unsigned)(av[c] > 0)) << c;
    }
    unsigned n1 = nib | (__shfl_xor(nib, 1) << 4);
    unsigned n2 = n1 | (__shfl_xor(n1, 2) << 8);
    unsigned n4 = n2 | (__shfl_xor(n2, 4) << 16);
    if ((t & 7) == 0) mwords[q * 32 + (t >> 3)] = n4;
  }
#pragma unroll
  for (int off = 32; off; off >>= 1) sum += __shfl_xor(sum, off);
  if ((t & 63) == 0) wsum[t >> 6] = sum;
  __syncthreads();
  if (t < 64) {
    unsigned long long mv = *(unsigned long long*)&mwords[t * 2];
    mask64[((long long)row << 6) + t] = mv;
  }
  if (t == 0) {
    float S = wsum[0] + wsum[1] + wsum[2] + wsum[3];
    float negc = (S > 0.f) ? -log2f(S) : -1.0e30f;
    st2[row] = make_float2(s1j, negc);
  }
}

// ---------------------------------------------------------------------------
// k3: bf16 partial[jc][b][k][i] = sum_{j in quarter} p[j,k]*Wh[j,i].
// Grid 512 = 4b x 8jc x 16kt (XCD-swizzled, kt innermost), 512 thr = 8 waves,
// k-tile 256 (wave w: k w*32..+31, all 128 i), no jq-split.
// LDS 36KB: whT dbuf 2x8KB @0 (granule G=gj*128+i, conflict-free b128 reads),
// mask 2x8KB @16K ([sec][j][16B]), stl float2[512] @32K. All via gload16.
// ---------------------------------------------------------------------------
__global__ __launch_bounds__(512, 4) void k3_pv(
    const unsigned short* __restrict__ whT, const float2* __restrict__ st2,
    const unsigned long long* __restrict__ mask64,
    const float* __restrict__ s2L, unsigned short* __restrict__ pbuf) {
  __shared__ __align__(16) char smem[36864];
  char* mbase = smem + 16384;
  float2* stl = (float2*)(smem + 32768);

  int t = threadIdx.x;
  int orig = blockIdx.x;
  int swz = (orig & 7) * 64 + (orig >> 3);  // bijective (512 % 8 == 0)
  int kt = swz & 15, jc = (swz >> 4) & 7, b = swz >> 7;
  int w = t >> 6, l = t & 63, hl = l >> 5, ln = l & 31;
  int jq0 = jc * JQ;
  long long brow = (long long)(b << 12);
  int k0 = kt << 8;
  float s2k = s2L[brow + k0 + w * 32 + ln];

  // stage-once: stl (4KB), mask (16KB)
  if (t < 256) gload16(st2 + brow + jq0 + t * 2, (char*)stl + t * 16);
  {
    const char* msrc =
        (const char*)(mask64 + ((brow + jq0 + t) << 6) + kt * 4);
    gload16(msrc, mbase + t * 16);              // k-in-tile 0..127
    gload16(msrc + 16, mbase + 8192 + t * 16);  // k-in-tile 128..255
  }
  // whT chunk 0: thread t -> granule G=t: gj=G>>7 (j-oct), gi=G&127 (i)
  const unsigned short* whTb = whT + ((long long)b << 19);
  int gj = t >> 7, gi = t & 127;
  const unsigned short* wsrc = whTb + (long long)gi * 4096 + jq0 + gj * 8;
  gload16(wsrc, smem + t * 16);
  __syncthreads();

  char* mwv = mbase + (w >> 2) * 8192 + (w & 3) * 4;  // this wave's k-word

  f32x16 acc[4];
#pragma unroll
  for (int q = 0; q < 4; ++q)
#pragma unroll
    for (int r = 0; r < 16; ++r) acc[q][r] = 0.f;

  for (int ch = 0; ch < NCH; ++ch) {
    int cur = ch & 1;
    if (ch + 1 < NCH)
      gload16(wsrc + (ch + 1) * 32, smem + (cur ^ 1) * 8192 + t * 16);
    char* wb = smem + cur * 8192;
    int jb = ch * 32 + hl * 8;
#pragma unroll
    for (int s = 0; s < 2; ++s) {
      short8 af;
#pragma unroll
      for (int e = 0; e < 8; ++e) {
        int ja = jb + s * 16 + e;
        float2 sc = stl[ja];
        unsigned int mv = *(unsigned int*)(mwv + ja * 16);
        float u = sc.x + s2k;
        float vL = fmaxf(u, ALPHA * u);
        float p = exp2f(vL + sc.y);
        p = ((mv >> ln) & 1u) ? p : 0.f;
        __hip_bfloat16 hb = __float2bfloat16(p);
        af[e] = *(short*)&hb;
      }
      int gbase = (2 * s + hl) * 2048;
#pragma unroll
      for (int q = 0; q < 4; ++q) {
        short8 bv = *(const short8*)(wb + gbase + ((q * 32 + ln) << 4));
        acc[q] =
            __builtin_amdgcn_mfma_f32_32x32x16_bf16(af, bv, acc[q], 0, 0, 0);
      }
    }
    __syncthreads();
  }

  // epilogue: bf16 partial store (slab jc)
  unsigned short* pb = pbuf + (long long)jc * SLAB + ((brow + k0) << 7);
#pragma unroll
  for (int q = 0; q < 4; ++q) {
#pragma unroll
    for (int r = 0; r < 16; ++r) {
      int kl = (r & 3) + ((r >> 2) << 3) + (hl << 2) + (w << 5);
      pb[kl * 128 + q * 32 + ln] = f2bf(acc[q][r]);
    }
  }
}

// ---------------------------------------------------------------------------
// k4: out = elu(sum_jc bf16 partial). Grid 1024 x 256, 8 elems/thread.
// ---------------------------------------------------------------------------
__global__ __launch_bounds__(256) void k4_reduce(
    const unsigned short* __restrict__ pbuf, float* __restrict__ out) {
  int base = (blockIdx.x * 256 + threadIdx.x) * 8;
  float s[8] = {0.f, 0.f, 0.f, 0.f, 0.f, 0.f, 0.f, 0.f};
#pragma unroll
  for (int sl = 0; sl < JC; ++sl) {
    ushort8 v = *(const ushort8*)(pbuf + (long long)sl * SLAB + base);
#pragma unroll
    for (int e = 0; e < 8; ++e)
      s[e] += __uint_as_float(((unsigned)(unsigned short)v[e]) << 16);
  }
  f32x4 o0, o1;
#pragma unroll
  for (int e = 0; e < 8; ++e) {
    float x = s[e];
    float y = x > 0.f ? x : expm1f(x);
    if (e < 4) o0[e] = y; else o1[e - 4] = y;
  }
  *(f32x4*)(out + base) = o0;
  *(f32x4*)(out + base + 4) = o1;
}

extern "C" void kernel_launch(void* const* d_in, const int* in_sizes, int n_in,
                              void* d_out, int out_size, void* d_ws,
                              size_t ws_size, hipStream_t stream) {
  const float* h = (const float*)d_in[0];
  const int* adj = (const int*)d_in[1];
  const float* W = (const float*)d_in[2];
  const float* a = (const float*)d_in[3];
  float* out = (float*)d_out;

  char* ws = (char*)d_ws;
  unsigned short* WT = (unsigned short*)ws;                  // 64 KB
  float* wa = (float*)(ws + 65536);                          // 2 KB
  unsigned short* whT = (unsigned short*)(ws + (1 << 20));   // 4 MB
  float* s1L = (float*)(ws + (5 << 20));                     // 64 KB
  float* s2L = s1L + 16384;                                  // 64 KB
  float2* st2 = (float2*)(ws + (5 << 20) + (128 << 10));     // 128 KB
  unsigned long long* mask64 =
      (unsigned long long*)(ws + (6 << 20));                 // 8 MB
  unsigned short* pbuf = (unsigned short*)(ws + (16 << 20)); // 32 MB bf16

  hipLaunchKernelGGL(k0_prep, dim3(9), dim3(256), 0, stream, W, a, WT, wa);
  hipLaunchKernelGGL(k1a_scores, dim3(4096), dim3(256), 0, stream, h, wa, s1L,
                     s2L);
  hipLaunchKernelGGL(k1b_wh, dim3(256), dim3(256), 0, stream, h, WT, whT);
  hipLaunchKernelGGL(k2_stats, dim3(16384), dim3(256), 0, stream, adj, s1L,
                     s2L, st2, mask64);
  hipLaunchKernelGGL(k3_pv, dim3(512), dim3(512), 0, stream, whT, st2, mask64,
                     s2L, pbuf);
  hipLaunchKernelGGL(k4_reduce, dim3(1024), dim3(256), 0, stream, pbuf, out);
}

// Round 6
// 122.319 us; speedup vs baseline: 1.5399x; 1.0529x over previous
//
#include <hip/hip_runtime.h>
#include <hip/hip_bf16.h>

#define ALPHA 0.2f
#define L2E 1.4426950408889634f

constexpr int Nn = 4096;
constexpr int FIN = 256;
constexpr int FOUT = 128;
constexpr int JC = 8;    // j-split for k3
constexpr int JQ = 512;  // j per k3 block
constexpr int NCH = 16;  // 32-j chunks per k3 block
constexpr long long SLAB = 2097152;  // 4*4096*128 elems per partial slab

typedef __attribute__((ext_vector_type(8))) short short8;
typedef __attribute__((ext_vector_type(8))) unsigned short ushort8;
typedef __attribute__((ext_vector_type(4))) float f32x4;
typedef __attribute__((ext_vector_type(16))) float f32x16;
typedef __attribute__((ext_vector_type(4))) int int4v;

__device__ __forceinline__ unsigned short f2bf(float x) {
  unsigned int u = __float_as_uint(x);
  unsigned int r = (u + 0x7fffu + ((u >> 16) & 1u)) >> 16;
  return (unsigned short)r;
}

__device__ __forceinline__ float bf2f(unsigned short v) {
  return __uint_as_float(((unsigned)v) << 16);
}

__device__ __forceinline__ void gload16(const void* g, void* l) {
  auto lp = (__attribute__((address_space(3))) void*)l;
  auto gp = (const __attribute__((address_space(1))) void*)g;
  __builtin_amdgcn_global_load_lds(gp, lp, 16, 0, 0);
}

// ---------------------------------------------------------------------------
// k0: WT bf16 [i=128][k=256] from W f32 [k][i] (LDS transpose). Grid 8.
// ---------------------------------------------------------------------------
__global__ __launch_bounds__(256) void k0_prep(
    const float* __restrict__ W, unsigned short* __restrict__ WT) {
  __shared__ float lw[32][132];
  int t = threadIdx.x;
  int kc0 = blockIdx.x * 32;
#pragma unroll
  for (int m = 0; m < 4; ++m) {
    int idx = t * 16 + m * 4;
    f32x4 v = *(const f32x4*)(W + kc0 * 128 + idx);
    int k = idx >> 7, i0 = idx & 127;
    *(f32x4*)&lw[k][i0] = v;
  }
  __syncthreads();
  int i = t >> 1, half = t & 1;
  unsigned short pk[16];
#pragma unroll
  for (int kk = 0; kk < 16; ++kk) pk[kk] = f2bf(lw[half * 16 + kk][i]);
  ushort8* dst = (ushort8*)(WT + i * 256 + kc0 + half * 16);
  dst[0] = *(ushort8*)&pk[0];
  dst[1] = *(ushort8*)&pk[8];
}

// ---------------------------------------------------------------------------
// k1b: Wh via mfma_16x16x32_bf16. 16-row blocks, grid 1024 (4 blocks/CU).
// Emits whT bf16 [b][i=128][n=4096] AND s1L/s2L (dot of bf16 Wh with a1/a2,
// scaled by log2 e). LDS 36KB: hb [16][16slot] @0 (4K), wt [128][16slot]
// @4096 (32K), tb [128][24] ushort aliases @0 after compute.
// ---------------------------------------------------------------------------
__global__ __launch_bounds__(256) void k1b_wh(
    const float* __restrict__ h, const unsigned short* __restrict__ WT,
    const float* __restrict__ a, unsigned short* __restrict__ whT,
    float* __restrict__ s1L, float* __restrict__ s2L) {
  __shared__ __align__(16) char smem[36864];
  int t = threadIdx.x;
  int w = t >> 6, l = t & 63, g = l >> 4, r = l & 15;
  int r0 = blockIdx.x * 16;
  int b = r0 >> 12, nbase = r0 & 4095;

  f32x4 acc[2];
  acc[0] = (f32x4){0.f, 0.f, 0.f, 0.f};
  acc[1] = (f32x4){0.f, 0.f, 0.f, 0.f};

  for (int kc = 0; kc < 2; ++kc) {
    __syncthreads();
    // stage h: row = t>>4, sec = t&15 (8 k = one 16B slot each)
    {
      int row = t >> 4, sec = t & 15;
      const f32x4* src =
          (const f32x4*)(h + (long long)(r0 + row) * 256 + kc * 128 + sec * 8);
      f32x4 v0 = src[0], v1 = src[1];
      unsigned int pk[4];
      pk[0] = ((unsigned)f2bf(v0.y) << 16) | f2bf(v0.x);
      pk[1] = ((unsigned)f2bf(v0.w) << 16) | f2bf(v0.z);
      pk[2] = ((unsigned)f2bf(v1.y) << 16) | f2bf(v1.x);
      pk[3] = ((unsigned)f2bf(v1.w) << 16) | f2bf(v1.z);
      *(ushort8*)(smem + row * 256 + ((sec ^ (row & 7)) << 4)) = *(ushort8*)pk;
    }
    // stage WT chunk: i = t>>1, pt = t&1 (8 slots each)
    {
      int i = t >> 1, pt = t & 1;
      const ushort8* src = (const ushort8*)(WT + i * 256 + kc * 128 + pt * 64);
#pragma unroll
      for (int m = 0; m < 8; ++m) {
        ushort8 v = src[m];
        int slot = pt * 8 + m;
        *(ushort8*)(smem + 4096 + i * 256 + ((slot ^ (i & 7)) << 4)) = v;
      }
    }
    __syncthreads();
#pragma unroll
    for (int kk = 0; kk < 4; ++kk) {
      short8 af =
          *(const short8*)(smem + r * 256 + (((kk * 4 + g) ^ (r & 7)) << 4));
#pragma unroll
      for (int s = 0; s < 2; ++s) {
        int i = w * 32 + s * 16 + r;
        short8 bf = *(const short8*)(smem + 4096 + i * 256 +
                                     (((kk * 4 + g) ^ (i & 7)) << 4));
        acc[s] =
            __builtin_amdgcn_mfma_f32_16x16x32_bf16(af, bf, acc[s], 0, 0, 0);
      }
    }
  }

  // transpose buffer tb [i=128][n=16 + 8 pad] ushort (aliases smem)
  __syncthreads();
  unsigned short* tb = (unsigned short*)smem;
#pragma unroll
  for (int s = 0; s < 2; ++s)
#pragma unroll
    for (int q = 0; q < 4; ++q)
      tb[(w * 32 + s * 16 + r) * 24 + g * 4 + q] = f2bf(acc[s][q]);
  __syncthreads();

  // whT store: i = t>>1, half = t&1 (16B each)
  {
    int i = t >> 1, half = t & 1;
    ushort8 v = *(const ushort8*)(tb + i * 24 + half * 8);
    *(ushort8*)(whT + (((long long)(b * 128 + i)) << 12) + nbase + half * 8) =
        v;
  }
  // s1/s2: n = t>>4, seg = t&15 covering i = seg*8..+7
  {
    int n = t >> 4, seg = t & 15;
    f32x4 a10 = *(const f32x4*)(a + seg * 8);
    f32x4 a11 = *(const f32x4*)(a + seg * 8 + 4);
    f32x4 a20 = *(const f32x4*)(a + 128 + seg * 8);
    f32x4 a21 = *(const f32x4*)(a + 128 + seg * 8 + 4);
    float v1 = 0.f, v2 = 0.f;
#pragma unroll
    for (int m = 0; m < 8; ++m) {
      float wh = bf2f(tb[(seg * 8 + m) * 24 + n]);
      float c1 = (m < 4) ? a10[m] : a11[m - 4];
      float c2 = (m < 4) ? a20[m] : a21[m - 4];
      v1 += wh * c1;
      v2 += wh * c2;
    }
#pragma unroll
    for (int off = 8; off; off >>= 1) {
      v1 += __shfl_xor(v1, off);
      v2 += __shfl_xor(v2, off);
    }
    if (seg == 0) {
      s1L[r0 + n] = v1 * L2E;
      s2L[r0 + n] = v2 * L2E;
    }
  }
}

// ---------------------------------------------------------------------------
// k2: block-per-row, coalesced NT int4 adj loads, single-pass no-max softmax
// in exp2 domain; mask via shfl_xor nibble merge. st2[row] = {s1L + negc,
// ALPHA*s1L + negc}; mask64[row][64]. Grid 16384 x 256.
// ---------------------------------------------------------------------------
__global__ __launch_bounds__(256) void k2_stats(
    const int* __restrict__ adj, const float* __restrict__ s1L,
    const float* __restrict__ s2L, float2* __restrict__ st2,
    unsigned long long* __restrict__ mask64) {
  __shared__ unsigned int mwords[128];
  __shared__ float wsum[4];
  int row = blockIdx.x;
  int b = row >> 12;
  int t = threadIdx.x;
  float s1j = s1L[row];
  const int4v* arow = (const int4v*)(adj + (long long)row * Nn);
  const f32x4* s2v = (const f32x4*)(s2L + (b << 12));

  float sum = 0.f;
#pragma unroll
  for (int q = 0; q < 4; ++q) {
    int4v av = __builtin_nontemporal_load(arow + q * 256 + t);
    f32x4 sv = s2v[q * 256 + t];
    unsigned nib = 0;
#pragma unroll
    for (int c = 0; c < 4; ++c) {
      float u = s1j + sv[c];
      float vL = fmaxf(u, ALPHA * u);
      float e = exp2f(vL);
      sum += (av[c] > 0) ? e : 0.f;
      nib |= ((unsigned)(av[c] > 0)) << c;
    }
    unsigned n1 = nib | (__shfl_xor(nib, 1) << 4);
    unsigned n2 = n1 | (__shfl_xor(n1, 2) << 8);
    unsigned n4 = n2 | (__shfl_xor(n2, 4) << 16);
    if ((t & 7) == 0) mwords[q * 32 + (t >> 3)] = n4;
  }
#pragma unroll
  for (int off = 32; off; off >>= 1) sum += __shfl_xor(sum, off);
  if ((t & 63) == 0) wsum[t >> 6] = sum;
  __syncthreads();
  if (t < 64) {
    unsigned long long mv = *(unsigned long long*)&mwords[t * 2];
    mask64[((long long)row << 6) + t] = mv;
  }
  if (t == 0) {
    float S = wsum[0] + wsum[1] + wsum[2] + wsum[3];
    float negc = (S > 0.f) ? -log2f(S) : -1.0e30f;
    st2[row] = make_float2(s1j + negc, ALPHA * s1j + negc);
  }
}

// ---------------------------------------------------------------------------
// k3: bf16 partial[jc][b][k][i] = sum_{j in quarter} p[j,k]*Wh[j,i].
// Grid 512 = 4b x 8jc x 16kt (XCD-swizzled), 512 thr = 8 waves, k-tile 256.
// LDS 36KB: whT dbuf 2x8KB @0 (granule layout), mask 16KB @16K, stl @32K.
// A-build: p = exp2(max(c1 + z1, c2 + z2)) masked, c from st2, z from s2L.
// ---------------------------------------------------------------------------
__global__ __launch_bounds__(512, 4) void k3_pv(
    const unsigned short* __restrict__ whT, const float2* __restrict__ st2,
    const unsigned long long* __restrict__ mask64,
    const float* __restrict__ s2L, unsigned short* __restrict__ pbuf) {
  __shared__ __align__(16) char smem[36864];
  char* mbase = smem + 16384;
  float2* stl = (float2*)(smem + 32768);

  int t = threadIdx.x;
  int orig = blockIdx.x;
  int swz = (orig & 7) * 64 + (orig >> 3);  // bijective (512 % 8 == 0)
  int kt = swz & 15, jc = (swz >> 4) & 7, b = swz >> 7;
  int w = t >> 6, l = t & 63, hl = l >> 5, ln = l & 31;
  int jq0 = jc * JQ;
  long long brow = (long long)(b << 12);
  int k0 = kt << 8;
  float z1 = s2L[brow + k0 + w * 32 + ln];
  float z2 = ALPHA * z1;

  // stage-once: stl (4KB), mask (16KB)
  if (t < 256) gload16(st2 + brow + jq0 + t * 2, (char*)stl + t * 16);
  {
    const char* msrc = (const char*)(mask64 + ((brow + jq0 + t) << 6) + kt * 4);
    gload16(msrc, mbase + t * 16);              // k-in-tile 0..127
    gload16(msrc + 16, mbase + 8192 + t * 16);  // k-in-tile 128..255
  }
  // whT chunk 0: thread t -> granule G=t: gj=G>>7 (j-oct), gi=G&127 (i)
  const unsigned short* whTb = whT + ((long long)b << 19);
  int gj = t >> 7, gi = t & 127;
  const unsigned short* wsrc = whTb + (long long)gi * 4096 + jq0 + gj * 8;
  gload16(wsrc, smem + t * 16);
  __syncthreads();

  char* mwv = mbase + (w >> 2) * 8192 + (w & 3) * 4;  // this wave's k-word

  f32x16 acc[4];
#pragma unroll
  for (int q = 0; q < 4; ++q)
#pragma unroll
    for (int r = 0; r < 16; ++r) acc[q][r] = 0.f;

  for (int ch = 0; ch < NCH; ++ch) {
    int cur = ch & 1;
    if (ch + 1 < NCH)
      gload16(wsrc + (ch + 1) * 32, smem + (cur ^ 1) * 8192 + t * 16);
    char* wb = smem + cur * 8192;
    int jb = ch * 32 + hl * 8;
#pragma unroll
    for (int s = 0; s < 2; ++s) {
      short8 af;
#pragma unroll
      for (int e = 0; e < 8; ++e) {
        int ja = jb + s * 16 + e;
        float2 sc = stl[ja];
        unsigned int mv = *(unsigned int*)(mwv + ja * 16);
        float e1 = sc.x + z1;
        float e2 = sc.y + z2;
        float p = exp2f(fmaxf(e1, e2));
        p = ((mv >> ln) & 1u) ? p : 0.f;
        __hip_bfloat16 hb = __float2bfloat16(p);
        af[e] = *(short*)&hb;
      }
      int gbase = (2 * s + hl) * 2048;
#pragma unroll
      for (int q = 0; q < 4; ++q) {
        short8 bv = *(const short8*)(wb + gbase + ((q * 32 + ln) << 4));
        acc[q] =
            __builtin_amdgcn_mfma_f32_32x32x16_bf16(af, bv, acc[q], 0, 0, 0);
      }
    }
    __syncthreads();
  }

  // epilogue: bf16 partial store (slab jc), nontemporal
  unsigned short* pb = pbuf + (long long)jc * SLAB + ((brow + k0) << 7);
#pragma unroll
  for (int q = 0; q < 4; ++q) {
#pragma unroll
    for (int r = 0; r < 16; ++r) {
      int kl = (r & 3) + ((r >> 2) << 3) + (hl << 2) + (w << 5);
      __builtin_nontemporal_store(f2bf(acc[q][r]),
                                  pb + kl * 128 + q * 32 + ln);
    }
  }
}

// ---------------------------------------------------------------------------
// k4: out = elu(sum_jc bf16 partial). Grid 1024 x 256, 8 elems/thread, NT.
// ---------------------------------------------------------------------------
__global__ __launch_bounds__(256) void k4_reduce(
    const unsigned short* __restrict__ pbuf, float* __restrict__ out) {
  int base = (blockIdx.x * 256 + threadIdx.x) * 8;
  float s[8] = {0.f, 0.f, 0.f, 0.f, 0.f, 0.f, 0.f, 0.f};
#pragma unroll
  for (int sl = 0; sl < JC; ++sl) {
    ushort8 v = __builtin_nontemporal_load(
        (const ushort8*)(pbuf + (long long)sl * SLAB + base));
#pragma unroll
    for (int e = 0; e < 8; ++e)
      s[e] += __uint_as_float(((unsigned)(unsigned short)v[e]) << 16);
  }
  f32x4 o0, o1;
#pragma unroll
  for (int e = 0; e < 8; ++e) {
    float x = s[e];
    float y = x > 0.f ? x : expm1f(x);
    if (e < 4) o0[e] = y; else o1[e - 4] = y;
  }
  *(f32x4*)(out + base) = o0;
  *(f32x4*)(out + base + 4) = o1;
}

extern "C" void kernel_launch(void* const* d_in, const int* in_sizes, int n_in,
                              void* d_out, int out_size, void* d_ws,
                              size_t ws_size, hipStream_t stream) {
  const float* h = (const float*)d_in[0];
  const int* adj = (const int*)d_in[1];
  const float* W = (const float*)d_in[2];
  const float* a = (const float*)d_in[3];
  float* out = (float*)d_out;

  char* ws = (char*)d_ws;
  unsigned short* WT = (unsigned short*)ws;                  // 64 KB
  unsigned short* whT = (unsigned short*)(ws + (1 << 20));   // 4 MB
  float* s1L = (float*)(ws + (5 << 20));                     // 64 KB
  float* s2L = s1L + 16384;                                  // 64 KB
  float2* st2 = (float2*)(ws + (5 << 20) + (128 << 10));     // 128 KB
  unsigned long long* mask64 =
      (unsigned long long*)(ws + (6 << 20));                 // 8 MB
  unsigned short* pbuf = (unsigned short*)(ws + (16 << 20)); // 32 MB bf16

  hipLaunchKernelGGL(k0_prep, dim3(8), dim3(256), 0, stream, W, WT);
  hipLaunchKernelGGL(k1b_wh, dim3(1024), dim3(256), 0, stream, h, WT, a, whT,
                     s1L, s2L);
  hipLaunchKernelGGL(k2_stats, dim3(16384), dim3(256), 0, stream, adj, s1L,
                     s2L, st2, mask64);
  hipLaunchKernelGGL(k3_pv, dim3(512), dim3(512), 0, stream, whT, st2, mask64,
                     s2L, pbuf);
  hipLaunchKernelGGL(k4_reduce, dim3(1024), dim3(256), 0, stream, pbuf, out);
}